// Round 8
// baseline (430.656 us; speedup 1.0000x reference)
//
#include <hip/hip_runtime.h>
#include <hip/hip_bf16.h>

#define NPTS 200000
#define INC  64
#define OUTC 128
#define KTAP 27
#define EPSV 1e-5f
#define BM   128
#define NSHADOW 32

typedef __attribute__((ext_vector_type(8))) short bf16x8;
typedef __attribute__((ext_vector_type(4))) float f32x4;

__device__ __forceinline__ unsigned short f2bf(float f) {
  unsigned int u = __float_as_uint(f);
  return (unsigned short)((u + 0x7FFFu + ((u >> 16) & 1u)) >> 16);
}

// Transposed (linear) bf16 weight image: per-tap 16KB block, byte(c,i) = c*128 + 2*i.
__global__ void prep_weight(const float* __restrict__ w, unsigned char* __restrict__ img) {
  int kn = blockIdx.x;
  const float* wk = w + kn * (INC * OUTC);
  unsigned char* dst = img + kn * (INC * OUTC * 2);
  for (int e = threadIdx.x; e < INC * OUTC; e += blockDim.x) {
    int c = e >> 6;
    int i = e & 63;
    unsigned short h = f2bf(wk[i * OUTC + c]);
    *(unsigned short*)(dst + c * 128 + i * 2) = h;
  }
}

// feats fp32 (N x 64) -> bf16 rows of 128B.
__global__ __launch_bounds__(256) void prep_feats(const float* __restrict__ f,
                                                  unsigned short* __restrict__ o) {
  size_t i = (size_t)blockIdx.x * 256 + threadIdx.x;
  float4 a = ((const float4*)f)[i * 2];
  float4 b = ((const float4*)f)[i * 2 + 1];
  ushort4 ha = make_ushort4(f2bf(a.x), f2bf(a.y), f2bf(a.z), f2bf(a.w));
  ushort4 hb = make_ushort4(f2bf(b.x), f2bf(b.y), f2bf(b.z), f2bf(b.w));
  ((ushort4*)o)[i * 2]     = ha;
  ((ushort4*)o)[i * 2 + 1] = hb;
}

// MODE 0: real (with tap-13 identity stream). MODE 3: hot-64-row gather
// (randomness removed, same insts). MODE 4: no barrier (lockstep removed,
// garbage output into sink; out overwritten by MODE 0 afterwards).
template<int MODE>
__global__ __launch_bounds__(512, 4) void conv_main(
    const unsigned short* __restrict__ fbf,
    const int*   __restrict__ nmap,
    const unsigned char* __restrict__ wimg,
    float* __restrict__ out,
    float* __restrict__ shadow)
{
  __shared__ __align__(16) unsigned char ldsA[2][BM * 128];    // 2 x 16KB
  __shared__ __align__(16) unsigned char ldsB[2][OUTC * 128];  // 2 x 16KB

  const int t    = threadIdx.x;
  const int lane = t & 63;
  const int w    = t >> 6;        // 0..7
  const int wm   = w >> 2;        // 0..1 : row half (64 rows)
  const int wn   = w & 3;         // 0..3 : col quarter (32 cols)
  const int n0   = blockIdx.x * BM;
  const int lr   = lane & 15;
  const int lg   = lane >> 4;
  const int srow = t >> 2;        // 0..127 staging row / col
  const int sch  = t & 3;         // 32B chunk within 128B row
  const unsigned swz = ((unsigned)(srow & 7)) << 4;

  const int n_st = n0 + srow;
  const int n_cl = (n_st < NPTS) ? n_st : (NPTS - 1);
  const bool rowok = (n_st < NPTS);

  f32x4 zv = {0.f, 0.f, 0.f, 0.f};
  f32x4 acc[4][2];
  #pragma unroll
  for (int i = 0; i < 4; ++i) { acc[i][0] = zv; acc[i][1] = zv; }

  auto ldidx = [&](int k) -> int {
    if (MODE == 0 && k == 13) return rowok ? n_cl : -1;  // center tap: identity
    int raw = nmap[(size_t)k * NPTS + n_cl];
    return rowok ? raw : -1;
  };
  // clamped masked gather of one row's 32B chunk (2 x bf16x8)
  auto gat = [&](int g, bf16x8& a, bf16x8& b) {
    int gc = (g >= 0) ? g : 0;
    if (MODE == 3) gc = (g >= 0) ? (g & 63) : 0;   // hot 8KB set
    const bf16x8* p = (const bf16x8*)(fbf + (size_t)gc * 64 + sch * 16);
    bf16x8 x = p[0], y = p[1];
    a = (g >= 0) ? x : (bf16x8)(short)0;
    b = (g >= 0) ? y : (bf16x8)(short)0;
  };
  auto ldB = [&](int k, bf16x8& a, bf16x8& b) {
    const bf16x8* p = (const bf16x8*)(wimg + (size_t)k * 16384 + t * 32);
    a = p[0]; b = p[1];
  };

  // ---- prologue ----
  bf16x8 vA0a, vA0b, vA1a, vA1b, vB0, vB1;
  int iA, iB;
  {
    int i0 = ldidx(0), i1 = ldidx(1);
    gat(i0, vA0a, vA0b);
    gat(i1, vA1a, vA1b);
    iA = ldidx(2); iB = ldidx(3);
    ldB(0, vB0, vB1);
  }

  const unsigned bst = ((unsigned)(srow * 128 + sch * 32)) ^ swz;

  auto tap = [&](int kn, int bsel, bf16x8& va, bf16x8& vb, int& inx,
                 bool doG, bool doB) {
    *(bf16x8*)(ldsA[bsel] + bst) = va;
    *(bf16x8*)(ldsA[bsel] + (bst ^ 16u)) = vb;
    *(bf16x8*)(ldsB[bsel] + bst) = vB0;
    *(bf16x8*)(ldsB[bsel] + (bst ^ 16u)) = vB1;
    if (MODE != 4) {
      asm volatile("s_waitcnt lgkmcnt(0)" ::: "memory");
      __builtin_amdgcn_s_barrier();
    }

    if (doG) gat(inx, va, vb);            // data for tap kn+2
    if (kn + 4 < KTAP) inx = ldidx(kn + 4);
    if (doB) ldB(kn + 1, vB0, vB1);       // B for tap kn+1

    #pragma unroll
    for (int kk = 0; kk < 2; ++kk) {
      const int kb = kk * 64 + lg * 16;
      bf16x8 av[4], bv[2];
      #pragma unroll
      for (int mf = 0; mf < 4; ++mf) {
        int row = wm * 64 + mf * 16 + lr;
        unsigned byte = ((unsigned)(row * 128 + kb)) ^ (((unsigned)(row & 7)) << 4);
        av[mf] = *(const bf16x8*)(ldsA[bsel] + byte);
      }
      #pragma unroll
      for (int nf = 0; nf < 2; ++nf) {
        int col = wn * 32 + nf * 16 + lr;
        unsigned byte = ((unsigned)(col * 128 + kb)) ^ (((unsigned)(col & 7)) << 4);
        bv[nf] = *(const bf16x8*)(ldsB[bsel] + byte);
      }
      #pragma unroll
      for (int mf = 0; mf < 4; ++mf)
        #pragma unroll
        for (int nf = 0; nf < 2; ++nf)
          acc[mf][nf] = __builtin_amdgcn_mfma_f32_16x16x32_bf16(av[mf], bv[nf], acc[mf][nf], 0, 0, 0);
    }
  };

  #pragma unroll 1
  for (int kn = 0; kn < KTAP - 1; kn += 2) {
    tap(kn,     0, vA0a, vA0b, iA, kn + 2 < KTAP, true);
    tap(kn + 1, 1, vA1a, vA1b, iB, kn + 3 < KTAP, true);
  }
  tap(KTAP - 1, 0, vA0a, vA0b, iA, false, false);

  // ---- epilogue: stores + wave-reduced channel sums -> 32-shadow atomics ----
  float* myshadow = shadow + (blockIdx.x & (NSHADOW - 1)) * 256;
  #pragma unroll
  for (int nf = 0; nf < 2; ++nf) {
    int c = wn * 32 + nf * 16 + lr;
    float s = 0.f, s2 = 0.f;
    #pragma unroll
    for (int mf = 0; mf < 4; ++mf) {
      #pragma unroll
      for (int r = 0; r < 4; ++r) {
        float v = acc[mf][nf][r];
        int n = n0 + wm * 64 + mf * 16 + lg * 4 + r;
        if (n < NPTS) {
          s += v; s2 += v * v;
          out[(size_t)n * OUTC + c] = v;
        }
      }
    }
    s  += __shfl_xor(s, 16);  s  += __shfl_xor(s, 32);
    s2 += __shfl_xor(s2, 16); s2 += __shfl_xor(s2, 32);
    if (lane < 16) {
      atomicAdd(&myshadow[c], s);
      atomicAdd(&myshadow[128 + c], s2);
    }
  }
}

__global__ void finalize_stats(const float* __restrict__ shadow,
                               const float* __restrict__ gamma,
                               const float* __restrict__ beta,
                               float* __restrict__ scale,
                               float* __restrict__ shift) {
  __shared__ float accs[256];
  int t = threadIdx.x;
  float s = 0.f;
  for (int b = 0; b < NSHADOW; ++b) s += shadow[b * 256 + t];
  accs[t] = s;
  __syncthreads();
  if (t < OUTC) {
    float mean = accs[t] * (1.0f / (float)NPTS);
    float var  = accs[128 + t] * (1.0f / (float)NPTS) - mean * mean;
    var = fmaxf(var, 0.f);
    float sc = gamma[t] * rsqrtf(var + EPSV);
    scale[t] = sc;
    shift[t] = beta[t] - mean * sc;
  }
}

__global__ __launch_bounds__(256) void norm_relu(float* __restrict__ out,
                                                 const float* __restrict__ scale,
                                                 const float* __restrict__ shift) {
  __shared__ float s_sc[OUTC], s_sh[OUTC];
  if (threadIdx.x < OUTC) {
    s_sc[threadIdx.x] = scale[threadIdx.x];
    s_sh[threadIdx.x] = shift[threadIdx.x];
  }
  __syncthreads();
  const long total = (long)NPTS * OUTC / 4;
  for (long i = (long)blockIdx.x * blockDim.x + threadIdx.x; i < total;
       i += (long)gridDim.x * blockDim.x) {
    float4 v = ((float4*)out)[i];
    int cb = (int)(i & 31) * 4;
    v.x = fmaxf(v.x * s_sc[cb + 0] + s_sh[cb + 0], 0.f);
    v.y = fmaxf(v.y * s_sc[cb + 1] + s_sh[cb + 1], 0.f);
    v.z = fmaxf(v.z * s_sc[cb + 2] + s_sh[cb + 2], 0.f);
    v.w = fmaxf(v.w * s_sc[cb + 3] + s_sh[cb + 3], 0.f);
    ((float4*)out)[i] = v;
  }
}

extern "C" void kernel_launch(void* const* d_in, const int* in_sizes, int n_in,
                              void* d_out, int out_size, void* d_ws, size_t ws_size,
                              hipStream_t stream) {
  (void)in_sizes; (void)n_in; (void)out_size; (void)ws_size;
  const float* feats  = (const float*)d_in[0];
  const float* weight = (const float*)d_in[1];
  const float* gamma  = (const float*)d_in[2];
  const float* beta   = (const float*)d_in[3];
  const int*   nmap   = (const int*)d_in[4];
  float* out = (float*)d_out;

  unsigned char* ws = (unsigned char*)d_ws;
  const size_t FBF_BYTES  = (size_t)NPTS * 64 * 2;     // 25,600,000
  const size_t WIMG_BYTES = (size_t)KTAP * 16384;      // 442,368
  unsigned short* fbf = (unsigned short*)ws;
  unsigned char* wimg = ws + FBF_BYTES;
  float* shadow  = (float*)(ws + FBF_BYTES + WIMG_BYTES);  // 32*256
  float* scale   = shadow + NSHADOW * 256;
  float* shift   = scale + 128;
  float* shadow2 = shift + 128;                            // ablation sink (proven ws range, R6)

  hipMemsetAsync(shadow, 0, NSHADOW * 256 * sizeof(float), stream);
  prep_weight<<<KTAP, 256, 0, stream>>>(weight, wimg);
  prep_feats<<<6250, 256, 0, stream>>>(feats, fbf);
  int grid = (NPTS + BM - 1) / BM;  // 1563
  // ---- ablations (junk results; out fully overwritten by MODE 0 below) ----
  conv_main<3><<<grid, 512, 0, stream>>>(fbf, nmap, wimg, out, shadow2);
  conv_main<4><<<grid, 512, 0, stream>>>(fbf, nmap, wimg, out, shadow2);
  // ---- real ----
  conv_main<0><<<grid, 512, 0, stream>>>(fbf, nmap, wimg, out, shadow);
  finalize_stats<<<1, 256, 0, stream>>>(shadow, gamma, beta, scale, shift);
  norm_relu<<<4096, 256, 0, stream>>>(out, scale, shift);
}

// Round 9
// 268.062 us; speedup vs baseline: 1.6066x; 1.6066x over previous
//
#include <hip/hip_runtime.h>
#include <hip/hip_bf16.h>

#define NPTS 200000
#define INC  64
#define OUTC 128
#define KTAP 27
#define EPSV 1e-5f
#define BM   256      // 16 waves x (32 exclusive rows x 64 cols)
#define NSHADOW 32

typedef __attribute__((ext_vector_type(8))) short bf16x8;
typedef __attribute__((ext_vector_type(4))) float f32x4;

__device__ __forceinline__ unsigned short f2bf(float f) {
  unsigned int u = __float_as_uint(f);
  return (unsigned short)((u + 0x7FFFu + ((u >> 16) & 1u)) >> 16);
}

// Fragment-packed bf16 weight image: 16KB per tap.
// chunk id = (ct*2+kk)*64 + lane ; byte = tap*16384 + id*16
// holds 8 bf16: w[tap][kk*32 + (lane>>4)*8 + j][ct*16 + (lane&15)], j=0..7
__global__ void prep_wfrag(const float* __restrict__ w, unsigned char* __restrict__ img) {
  int tap = blockIdx.x;
  const float* wk = w + tap * (INC * OUTC);
  for (int id = threadIdx.x; id < 1024; id += blockDim.x) {
    int lane = id & 63;
    int ck   = id >> 6;        // ct*2+kk
    int ct   = ck >> 1, kk = ck & 1;
    int c    = ct * 16 + (lane & 15);
    int k0   = kk * 32 + (lane >> 4) * 8;
    ushort4 lo, hi;
    lo.x = f2bf(wk[(k0+0)*OUTC + c]); lo.y = f2bf(wk[(k0+1)*OUTC + c]);
    lo.z = f2bf(wk[(k0+2)*OUTC + c]); lo.w = f2bf(wk[(k0+3)*OUTC + c]);
    hi.x = f2bf(wk[(k0+4)*OUTC + c]); hi.y = f2bf(wk[(k0+5)*OUTC + c]);
    hi.z = f2bf(wk[(k0+6)*OUTC + c]); hi.w = f2bf(wk[(k0+7)*OUTC + c]);
    unsigned char* d = img + (size_t)tap * 16384 + (size_t)id * 16;
    *(ushort4*)d       = lo;
    *(ushort4*)(d + 8) = hi;
  }
}

// feats fp32 (N x 64) -> bf16 rows of 128B.
__global__ __launch_bounds__(256) void prep_feats(const float* __restrict__ f,
                                                  unsigned short* __restrict__ o) {
  size_t i = (size_t)blockIdx.x * 256 + threadIdx.x;
  float4 a = ((const float4*)f)[i * 2];
  float4 b = ((const float4*)f)[i * 2 + 1];
  ushort4 ha = make_ushort4(f2bf(a.x), f2bf(a.y), f2bf(a.z), f2bf(a.w));
  ushort4 hb = make_ushort4(f2bf(b.x), f2bf(b.y), f2bf(b.z), f2bf(b.w));
  ((ushort4*)o)[i * 2]     = ha;
  ((ushort4*)o)[i * 2 + 1] = hb;
}

__global__ __launch_bounds__(1024, 4) void conv_main(
    const unsigned short* __restrict__ fbf,
    const int*   __restrict__ nmap,
    const unsigned char* __restrict__ fimg,
    float* __restrict__ out,
    float* __restrict__ shadow)
{
  // wave-private transpose patches (no cross-wave sharing -> no barriers)
  __shared__ float patch[16][16][68];   // 69632 B

  const int t    = threadIdx.x;
  const int lane = t & 63;
  const int w    = t >> 6;       // 0..15
  const int ch   = w & 1;        // col half (64 cols)
  const int wr   = w >> 1;       // 0..7 row group (32 rows, exclusive)
  const int n0   = blockIdx.x * BM;
  const int l15  = lane & 15;
  const int lg   = lane >> 4;    // 0..3

  f32x4 zv = {0.f, 0.f, 0.f, 0.f};
  f32x4 acc[2][4];
  #pragma unroll
  for (int i = 0; i < 2; ++i)
    #pragma unroll
    for (int j = 0; j < 4; ++j) acc[i][j] = zv;

  // this lane's two gather rows (rowtiles rt=0,1)
  const int nr0 = n0 + wr * 32 + l15;
  const int nr1 = nr0 + 16;
  const bool ok0 = (nr0 < NPTS), ok1 = (nr1 < NPTS);
  const int nc0 = ok0 ? nr0 : (NPTS - 1);
  const int nc1 = ok1 ? nr1 : (NPTS - 1);

  auto ldidx = [&](int k, int ncl, bool ok) -> int {
    if (k == 13) return ok ? ncl : -1;          // center tap: identity, no load
    int raw = nmap[(size_t)k * NPTS + ncl];
    return ok ? raw : -1;
  };
  // direct-to-fragment gather: lane holds A[row=l15][k = kk*32 + lg*8 .. +8]
  auto gfrag = [&](int g, int kk) -> bf16x8 {
    int gc = (g >= 0) ? g : 0;
    return *(const bf16x8*)((const unsigned char*)fbf +
                            (size_t)gc * 128 + kk * 64 + lg * 16);
  };

  // prologue: g(0), idx(1), A(0)
  int i0 = ldidx(0, nc0, ok0), i1 = ldidx(0, nc1, ok1);
  int x0 = ldidx(1, nc0, ok0), x1 = ldidx(1, nc1, ok1);
  bf16x8 a00 = gfrag(i0, 0), a01 = gfrag(i0, 1);
  bf16x8 a10 = gfrag(i1, 0), a11 = gfrag(i1, 1);

  const unsigned char* fb = fimg + (size_t)(ch * 4) * 2048 + (size_t)lane * 16;

  #pragma unroll 1
  for (int kn = 0; kn < KTAP; ++kn) {
    // idx(kn+2)
    int y0 = -1, y1 = -1;
    if (kn + 2 < KTAP) {
      y0 = ldidx(kn + 2, nc0, ok0);
      y1 = ldidx(kn + 2, nc1, ok1);
    }
    // B(kn): fragment-packed, fully coalesced, L1/L2-hot
    bf16x8 b[8];
    {
      const unsigned char* bp = fb + (size_t)kn * 16384;
      #pragma unroll
      for (int i = 0; i < 4; ++i) {
        b[i * 2 + 0] = *(const bf16x8*)(bp + (i * 2 + 0) * 1024);
        b[i * 2 + 1] = *(const bf16x8*)(bp + (i * 2 + 1) * 1024);
      }
    }
    // A(kn+1) gathers (depth-1)
    bf16x8 na00, na01, na10, na11;
    if (kn + 1 < KTAP) {
      na00 = gfrag(x0, 0); na01 = gfrag(x0, 1);
      na10 = gfrag(x1, 0); na11 = gfrag(x1, 1);
    }
    // mask A(kn)
    bf16x8 z = (bf16x8)(short)0;
    bf16x8 m00 = (i0 >= 0) ? a00 : z, m01 = (i0 >= 0) ? a01 : z;
    bf16x8 m10 = (i1 >= 0) ? a10 : z, m11 = (i1 >= 0) ? a11 : z;
    // 16 MFMAs
    #pragma unroll
    for (int nf = 0; nf < 4; ++nf) {
      acc[0][nf] = __builtin_amdgcn_mfma_f32_16x16x32_bf16(m00, b[nf*2+0], acc[0][nf], 0, 0, 0);
      acc[0][nf] = __builtin_amdgcn_mfma_f32_16x16x32_bf16(m01, b[nf*2+1], acc[0][nf], 0, 0, 0);
      acc[1][nf] = __builtin_amdgcn_mfma_f32_16x16x32_bf16(m10, b[nf*2+0], acc[1][nf], 0, 0, 0);
      acc[1][nf] = __builtin_amdgcn_mfma_f32_16x16x32_bf16(m11, b[nf*2+1], acc[1][nf], 0, 0, 0);
    }
    // rotate pipeline
    a00 = na00; a01 = na01; a10 = na10; a11 = na11;
    i0 = x0; i1 = x1; x0 = y0; x1 = y1;
  }

  // ---- stats (invalid rows carry exact zeros -> no bias) ----
  float* mysh = shadow + (blockIdx.x & (NSHADOW - 1)) * 256;
  #pragma unroll
  for (int nf = 0; nf < 4; ++nf) {
    int c = ch * 64 + nf * 16 + l15;
    float s = 0.f, s2 = 0.f;
    #pragma unroll
    for (int mf = 0; mf < 2; ++mf)
      #pragma unroll
      for (int r = 0; r < 4; ++r) {
        float v = acc[mf][nf][r];
        s += v; s2 += v * v;
      }
    s  += __shfl_xor(s, 16);  s  += __shfl_xor(s, 32);
    s2 += __shfl_xor(s2, 16); s2 += __shfl_xor(s2, 32);
    if (lane < 16) {
      atomicAdd(&mysh[c], s);
      atomicAdd(&mysh[128 + c], s2);
    }
  }

  // ---- wave-private LDS transpose -> coalesced stores (no barrier) ----
  #pragma unroll
  for (int mf = 0; mf < 2; ++mf) {
    #pragma unroll
    for (int nf = 0; nf < 4; ++nf)
      #pragma unroll
      for (int r = 0; r < 4; ++r)
        patch[w][lg * 4 + r][nf * 16 + l15] = acc[mf][nf][r];
    // compiler inserts lgkmcnt for the RAW dependency below
    int prow = lane >> 2;          // 0..15
    int q    = lane & 3;           // 16-col quarter
    int gr   = n0 + wr * 32 + mf * 16 + prow;
    if (gr < NPTS) {
      const float* src = &patch[w][prow][q * 16];
      float* dst = out + (size_t)gr * OUTC + ch * 64 + q * 16;
      #pragma unroll
      for (int i = 0; i < 4; ++i)
        ((float4*)dst)[i] = ((const float4*)src)[i];
    }
  }
}

__global__ void finalize_stats(const float* __restrict__ shadow,
                               const float* __restrict__ gamma,
                               const float* __restrict__ beta,
                               float* __restrict__ scale,
                               float* __restrict__ shift) {
  __shared__ float accs[256];
  int t = threadIdx.x;
  float s = 0.f;
  for (int b = 0; b < NSHADOW; ++b) s += shadow[b * 256 + t];
  accs[t] = s;
  __syncthreads();
  if (t < OUTC) {
    float mean = accs[t] * (1.0f / (float)NPTS);
    float var  = accs[128 + t] * (1.0f / (float)NPTS) - mean * mean;
    var = fmaxf(var, 0.f);
    float sc = gamma[t] * rsqrtf(var + EPSV);
    scale[t] = sc;
    shift[t] = beta[t] - mean * sc;
  }
}

__global__ __launch_bounds__(256) void norm_relu(float* __restrict__ out,
                                                 const float* __restrict__ scale,
                                                 const float* __restrict__ shift) {
  __shared__ float s_sc[OUTC], s_sh[OUTC];
  if (threadIdx.x < OUTC) {
    s_sc[threadIdx.x] = scale[threadIdx.x];
    s_sh[threadIdx.x] = shift[threadIdx.x];
  }
  __syncthreads();
  const long total = (long)NPTS * OUTC / 4;
  for (long i = (long)blockIdx.x * blockDim.x + threadIdx.x; i < total;
       i += (long)gridDim.x * blockDim.x) {
    float4 v = ((float4*)out)[i];
    int cb = (int)(i & 31) * 4;
    v.x = fmaxf(v.x * s_sc[cb + 0] + s_sh[cb + 0], 0.f);
    v.y = fmaxf(v.y * s_sc[cb + 1] + s_sh[cb + 1], 0.f);
    v.z = fmaxf(v.z * s_sc[cb + 2] + s_sh[cb + 2], 0.f);
    v.w = fmaxf(v.w * s_sc[cb + 3] + s_sh[cb + 3], 0.f);
    ((float4*)out)[i] = v;
  }
}

extern "C" void kernel_launch(void* const* d_in, const int* in_sizes, int n_in,
                              void* d_out, int out_size, void* d_ws, size_t ws_size,
                              hipStream_t stream) {
  (void)in_sizes; (void)n_in; (void)out_size; (void)ws_size;
  const float* feats  = (const float*)d_in[0];
  const float* weight = (const float*)d_in[1];
  const float* gamma  = (const float*)d_in[2];
  const float* beta   = (const float*)d_in[3];
  const int*   nmap   = (const int*)d_in[4];
  float* out = (float*)d_out;

  unsigned char* ws = (unsigned char*)d_ws;
  const size_t FBF_BYTES  = (size_t)NPTS * 64 * 2;     // 25,600,000
  const size_t FIMG_BYTES = (size_t)KTAP * 16384;      // 442,368
  unsigned short* fbf = (unsigned short*)ws;
  unsigned char* fimg = ws + FBF_BYTES;
  float* shadow = (float*)(ws + FBF_BYTES + FIMG_BYTES);  // 32*256
  float* scale  = shadow + NSHADOW * 256;
  float* shift  = scale + 128;

  hipMemsetAsync(shadow, 0, NSHADOW * 256 * sizeof(float), stream);
  prep_wfrag<<<KTAP, 256, 0, stream>>>(weight, fimg);
  prep_feats<<<6250, 256, 0, stream>>>(feats, fbf);
  int grid = (NPTS + BM - 1) / BM;  // 782
  conv_main<<<grid, 1024, 0, stream>>>(fbf, nmap, fimg, out, shadow);
  finalize_stats<<<1, 256, 0, stream>>>(shadow, gamma, beta, scale, shift);
  norm_relu<<<4096, 256, 0, stream>>>(out, scale, shift);
}

// Round 11
// 175.934 us; speedup vs baseline: 2.4478x; 1.5237x over previous
//
#include <hip/hip_runtime.h>
#include <hip/hip_bf16.h>

#define NPTS 200000
#define INC  64
#define OUTC 128
#define KTAP 27
#define EPSV 1e-5f
#define BM   128
#define NSHADOW 32

typedef __attribute__((ext_vector_type(8))) short bf16x8;
typedef __attribute__((ext_vector_type(4))) float f32x4;

__device__ __forceinline__ unsigned short f2bf(float f) {
  unsigned int u = __float_as_uint(f);
  return (unsigned short)((u + 0x7FFFu + ((u >> 16) & 1u)) >> 16);
}

// Fragment-packed bf16 weight image, 16KB/tap (R9-verified layout):
// chunk id=(ct*2+kk)*64+lane holds w[kk*32+(lane>>4)*8+j][ct*16+(lane&15)], j=0..7
__global__ void prep_wfrag(const float* __restrict__ w, unsigned char* __restrict__ img) {
  int tap = blockIdx.x;
  const float* wk = w + tap * (INC * OUTC);
  for (int id = threadIdx.x; id < 1024; id += blockDim.x) {
    int lane = id & 63;
    int ck   = id >> 6;
    int ct   = ck >> 1, kk = ck & 1;
    int c    = ct * 16 + (lane & 15);
    int k0   = kk * 32 + (lane >> 4) * 8;
    ushort4 lo, hi;
    lo.x = f2bf(wk[(k0+0)*OUTC + c]); lo.y = f2bf(wk[(k0+1)*OUTC + c]);
    lo.z = f2bf(wk[(k0+2)*OUTC + c]); lo.w = f2bf(wk[(k0+3)*OUTC + c]);
    hi.x = f2bf(wk[(k0+4)*OUTC + c]); hi.y = f2bf(wk[(k0+5)*OUTC + c]);
    hi.z = f2bf(wk[(k0+6)*OUTC + c]); hi.w = f2bf(wk[(k0+7)*OUTC + c]);
    unsigned char* d = img + (size_t)tap * 16384 + (size_t)id * 16;
    *(ushort4*)d       = lo;
    *(ushort4*)(d + 8) = hi;
  }
}

// feats fp32 (N x 64) -> bf16 rows of 128B.
__global__ __launch_bounds__(256) void prep_feats(const float* __restrict__ f,
                                                  unsigned short* __restrict__ o) {
  size_t i = (size_t)blockIdx.x * 256 + threadIdx.x;
  float4 a = ((const float4*)f)[i * 2];
  float4 b = ((const float4*)f)[i * 2 + 1];
  ushort4 ha = make_ushort4(f2bf(a.x), f2bf(a.y), f2bf(a.z), f2bf(a.w));
  ushort4 hb = make_ushort4(f2bf(b.x), f2bf(b.y), f2bf(b.z), f2bf(b.w));
  ((ushort4*)o)[i * 2]     = ha;
  ((ushort4*)o)[i * 2 + 1] = hb;
}

__global__ __launch_bounds__(512, 4) void conv_main(
    const unsigned short* __restrict__ fbf,   // NPTS+1 rows; row NPTS is zeros
    const int*   __restrict__ nmap,
    const unsigned char* __restrict__ wimg,
    float* __restrict__ out,
    float* __restrict__ shadow)
{
  __shared__ __align__(16) unsigned char ldsB[4][16384];   // 64KB: one 4-tap group

  const int t    = threadIdx.x;
  const int lane = t & 63;
  const int w    = t >> 6;       // 0..7
  const int cg   = w & 1;        // col group (64 cols)
  const int rg   = w >> 1;       // row group (32 rows, wave-exclusive)
  const int n0   = blockIdx.x * BM;
  const int l15  = lane & 15;
  const int lg   = lane >> 4;

  f32x4 zv = {0.f, 0.f, 0.f, 0.f};
  f32x4 acc[2][4];
  #pragma unroll
  for (int i = 0; i < 2; ++i)
    #pragma unroll
    for (int j = 0; j < 4; ++j) acc[i][j] = zv;

  const int nr0 = n0 + rg * 32 + l15;
  const int nr1 = nr0 + 16;
  const bool ok0 = nr0 < NPTS, ok1 = nr1 < NPTS;
  const int nc0 = ok0 ? nr0 : (NPTS - 1);
  const int nc1 = ok1 ? nr1 : (NPTS - 1);

  const unsigned char* fbp = (const unsigned char*)fbf;
  // invalid (g<0) or tail row -> zero row NPTS: no masking anywhere
  auto gp = [&](int g, bool ok) -> const unsigned char* {
    int gc = (g >= 0) ? g : NPTS;
    gc = ok ? gc : NPTS;
    return fbp + (size_t)gc * 128 + lg * 16;
  };

  // stage taps [kbase, kbase+ntap) into slots 0..ntap-1 (linear copy via glds)
  auto stage = [&](int kbase, int ntap) {
    for (int kt = 0; kt < ntap; ++kt) {
      const unsigned char* src = wimg + (size_t)(kbase + kt) * 16384 + (size_t)t * 16;
      __builtin_amdgcn_global_load_lds(
          (const __attribute__((address_space(1))) void*)src,
          (__attribute__((address_space(3))) void*)(&ldsB[kt][t * 16]), 16, 0, 0);
      __builtin_amdgcn_global_load_lds(
          (const __attribute__((address_space(1))) void*)(src + 8192),
          (__attribute__((address_space(3))) void*)(&ldsB[kt][t * 16 + 8192]), 16, 0, 0);
    }
  };

  const unsigned bb = (unsigned)(cg * 8192 + lane * 16);

  // one tap, no syncs: issue A(kn+2) gathers + idx(kn+4), MFMA with A(kn),B(slot)
  auto do_tap = [&](int kn, int slot,
                    bf16x8& A0, bf16x8& A1, bf16x8& A2, bf16x8& A3,
                    int& Q0, int& Q1, bool doG) {
    const unsigned char* bufR = ldsB[slot];
    bf16x8 nA0, nA1, nA2, nA3;
    if (doG) {
      const unsigned char* p0 = gp(Q0, ok0);
      const unsigned char* p1 = gp(Q1, ok1);
      nA0 = *(const bf16x8*)p0; nA1 = *(const bf16x8*)(p0 + 64);
      nA2 = *(const bf16x8*)p1; nA3 = *(const bf16x8*)(p1 + 64);
    }
    int kq = (kn + 4 < KTAP) ? (kn + 4) : (KTAP - 1);
    int nQ0 = nmap[(size_t)kq * NPTS + nc0];
    int nQ1 = nmap[(size_t)kq * NPTS + nc1];
    #pragma unroll
    for (int kk = 0; kk < 2; ++kk) {
      bf16x8 b0 = *(const bf16x8*)(bufR + bb + kk * 1024 + 0 * 2048);
      bf16x8 b1 = *(const bf16x8*)(bufR + bb + kk * 1024 + 1 * 2048);
      bf16x8 b2 = *(const bf16x8*)(bufR + bb + kk * 1024 + 2 * 2048);
      bf16x8 b3 = *(const bf16x8*)(bufR + bb + kk * 1024 + 3 * 2048);
      bf16x8 a0 = kk ? A1 : A0;
      bf16x8 a1 = kk ? A3 : A2;
      acc[0][0] = __builtin_amdgcn_mfma_f32_16x16x32_bf16(a0, b0, acc[0][0], 0, 0, 0);
      acc[0][1] = __builtin_amdgcn_mfma_f32_16x16x32_bf16(a0, b1, acc[0][1], 0, 0, 0);
      acc[0][2] = __builtin_amdgcn_mfma_f32_16x16x32_bf16(a0, b2, acc[0][2], 0, 0, 0);
      acc[0][3] = __builtin_amdgcn_mfma_f32_16x16x32_bf16(a0, b3, acc[0][3], 0, 0, 0);
      acc[1][0] = __builtin_amdgcn_mfma_f32_16x16x32_bf16(a1, b0, acc[1][0], 0, 0, 0);
      acc[1][1] = __builtin_amdgcn_mfma_f32_16x16x32_bf16(a1, b1, acc[1][1], 0, 0, 0);
      acc[1][2] = __builtin_amdgcn_mfma_f32_16x16x32_bf16(a1, b2, acc[1][2], 0, 0, 0);
      acc[1][3] = __builtin_amdgcn_mfma_f32_16x16x32_bf16(a1, b3, acc[1][3], 0, 0, 0);
    }
    if (doG) { A0 = nA0; A1 = nA1; A2 = nA2; A3 = nA3; }
    Q0 = nQ0; Q1 = nQ1;
  };

  // ---- prologue: idx taps 0..3; A(0), A(1); stage group 0 ----
  int j00 = nmap[nc0],                     j01 = nmap[nc1];
  int j10 = nmap[(size_t)NPTS + nc0],      j11 = nmap[(size_t)NPTS + nc1];
  int q00 = nmap[(size_t)2 * NPTS + nc0],  q01 = nmap[(size_t)2 * NPTS + nc1];
  int q10 = nmap[(size_t)3 * NPTS + nc0],  q11 = nmap[(size_t)3 * NPTS + nc1];

  bf16x8 aC0, aC1, aC2, aC3;   // even taps
  bf16x8 aN0, aN1, aN2, aN3;   // odd taps
  { const unsigned char* p = gp(j00, ok0); aC0 = *(const bf16x8*)p; aC1 = *(const bf16x8*)(p + 64); }
  { const unsigned char* p = gp(j01, ok1); aC2 = *(const bf16x8*)p; aC3 = *(const bf16x8*)(p + 64); }
  { const unsigned char* p = gp(j10, ok0); aN0 = *(const bf16x8*)p; aN1 = *(const bf16x8*)(p + 64); }
  { const unsigned char* p = gp(j11, ok1); aN2 = *(const bf16x8*)p; aN3 = *(const bf16x8*)(p + 64); }

  stage(0, 4);
  __syncthreads();   // group 0 B staged (full drain; correctness by construction)

  // ---- 6 groups of 4 taps; barrier pair only at group boundary ----
  #pragma unroll 1
  for (int g = 0; g < 6; ++g) {
    int kb = g * 4;
    do_tap(kb + 0, 0, aC0, aC1, aC2, aC3, q00, q01, true);
    do_tap(kb + 1, 1, aN0, aN1, aN2, aN3, q10, q11, true);
    do_tap(kb + 2, 2, aC0, aC1, aC2, aC3, q00, q01, true);
    do_tap(kb + 3, 3, aN0, aN1, aN2, aN3, q10, q11, true);
    __syncthreads();                       // readers done with slots 0..3
    stage(kb + 4, (g < 5) ? 4 : 3);        // next group (tail: taps 24..26)
    __syncthreads();                       // staging complete
  }
  // ---- tail group: taps 24,25,26 in slots 0,1,2 ----
  do_tap(24, 0, aC0, aC1, aC2, aC3, q00, q01, true);
  do_tap(25, 1, aN0, aN1, aN2, aN3, q10, q11, true);
  do_tap(26, 2, aC0, aC1, aC2, aC3, q00, q01, false);

  // ---- epilogue: guarded stores + wave-reduced sums -> 32-shadow atomics ----
  float* mysh = shadow + (blockIdx.x & (NSHADOW - 1)) * 256;
  #pragma unroll
  for (int nf = 0; nf < 4; ++nf) {
    int c = cg * 64 + nf * 16 + l15;
    float s = 0.f, s2 = 0.f;
    #pragma unroll
    for (int rt = 0; rt < 2; ++rt) {
      #pragma unroll
      for (int r = 0; r < 4; ++r) {
        float v = acc[rt][nf][r];
        int n = n0 + rg * 32 + rt * 16 + lg * 4 + r;
        if (n < NPTS) {
          s += v; s2 += v * v;
          out[(size_t)n * OUTC + c] = v;
        }
      }
    }
    s  += __shfl_xor(s, 16);  s  += __shfl_xor(s, 32);
    s2 += __shfl_xor(s2, 16); s2 += __shfl_xor(s2, 32);
    if (lane < 16) {
      atomicAdd(&mysh[c], s);
      atomicAdd(&mysh[128 + c], s2);
    }
  }
}

__global__ void finalize_stats(const float* __restrict__ shadow,
                               const float* __restrict__ gamma,
                               const float* __restrict__ beta,
                               float* __restrict__ scale,
                               float* __restrict__ shift) {
  __shared__ float accs[256];
  int t = threadIdx.x;
  float s = 0.f;
  for (int b = 0; b < NSHADOW; ++b) s += shadow[b * 256 + t];
  accs[t] = s;
  __syncthreads();
  if (t < OUTC) {
    float mean = accs[t] * (1.0f / (float)NPTS);
    float var  = accs[128 + t] * (1.0f / (float)NPTS) - mean * mean;
    var = fmaxf(var, 0.f);
    float sc = gamma[t] * rsqrtf(var + EPSV);
    scale[t] = sc;
    shift[t] = beta[t] - mean * sc;
  }
}

__global__ __launch_bounds__(256) void norm_relu(float* __restrict__ out,
                                                 const float* __restrict__ scale,
                                                 const float* __restrict__ shift) {
  __shared__ float s_sc[OUTC], s_sh[OUTC];
  if (threadIdx.x < OUTC) {
    s_sc[threadIdx.x] = scale[threadIdx.x];
    s_sh[threadIdx.x] = shift[threadIdx.x];
  }
  __syncthreads();
  const long total = (long)NPTS * OUTC / 4;
  for (long i = (long)blockIdx.x * blockDim.x + threadIdx.x; i < total;
       i += (long)gridDim.x * blockDim.x) {
    float4 v = ((float4*)out)[i];
    int cb = (int)(i & 31) * 4;
    v.x = fmaxf(v.x * s_sc[cb + 0] + s_sh[cb + 0], 0.f);
    v.y = fmaxf(v.y * s_sc[cb + 1] + s_sh[cb + 1], 0.f);
    v.z = fmaxf(v.z * s_sc[cb + 2] + s_sh[cb + 2], 0.f);
    v.w = fmaxf(v.w * s_sc[cb + 3] + s_sh[cb + 3], 0.f);
    ((float4*)out)[i] = v;
  }
}

extern "C" void kernel_launch(void* const* d_in, const int* in_sizes, int n_in,
                              void* d_out, int out_size, void* d_ws, size_t ws_size,
                              hipStream_t stream) {
  (void)in_sizes; (void)n_in; (void)out_size; (void)ws_size;
  const float* feats  = (const float*)d_in[0];
  const float* weight = (const float*)d_in[1];
  const float* gamma  = (const float*)d_in[2];
  const float* beta   = (const float*)d_in[3];
  const int*   nmap   = (const int*)d_in[4];
  float* out = (float*)d_out;

  unsigned char* ws = (unsigned char*)d_ws;
  const size_t FBF_BYTES  = (size_t)(NPTS + 1) * 128;  // 25,600,128 (+ zero row)
  const size_t WIMG_BYTES = (size_t)KTAP * 16384;      // 442,368
  unsigned short* fbf = (unsigned short*)ws;
  unsigned char* wimg = ws + FBF_BYTES;
  float* shadow = (float*)(ws + FBF_BYTES + WIMG_BYTES);  // 32*256
  float* scale  = shadow + NSHADOW * 256;
  float* shift  = scale + 128;

  hipMemsetAsync(shadow, 0, NSHADOW * 256 * sizeof(float), stream);
  hipMemsetAsync(fbf + (size_t)NPTS * 64, 0, 128, stream);   // zero row
  prep_wfrag<<<KTAP, 256, 0, stream>>>(weight, wimg);
  prep_feats<<<6250, 256, 0, stream>>>(feats, fbf);
  int grid = (NPTS + BM - 1) / BM;  // 1563
  conv_main<<<grid, 512, 0, stream>>>(fbf, nmap, wimg, out, shadow);
  finalize_stats<<<1, 256, 0, stream>>>(shadow, gamma, beta, scale, shift);
  norm_relu<<<4096, 256, 0, stream>>>(out, scale, shift);
}